// Round 15
// baseline (142.982 us; speedup 1.0000x reference)
//
#include <hip/hip_runtime.h>
#include <stdint.h>

#define NNODES 1024
#define NGRAPH 128
#define TOPK   16384
#define EQCAP  4096

typedef float vfloat4 __attribute__((ext_vector_type(4)));

// Order-preserving monotone map fp32 -> u32 (larger float => larger key).
__device__ __forceinline__ uint32_t fkey(float x) {
    uint32_t u = __float_as_uint(x);
    return (u & 0x80000000u) ? ~u : (u | 0x80000000u);
}
// Exact bit-level inverse of fkey (validated R6/R9/R11).
__device__ __forceinline__ float inv_fkey(uint32_t k) {
    uint32_t u = (k & 0x80000000u) ? (k & 0x7FFFFFFFu) : ~k;
    return __uint_as_float(u);
}
// Compiler-only fence for wave-synchronous LDS (no HW cost).
__device__ __forceinline__ void wavefence() {
    __builtin_amdgcn_wave_barrier();
    asm volatile("" ::: "memory");
}
// Wave64 sum on the VALU pipe via DPP (zero DS-pipe traffic) -- R14-validated.
// Lane 63 holds the full sum. bound_ctrl=true: OOB lanes contribute 0.
__device__ __forceinline__ uint32_t wave_sum_dpp(uint32_t v) {
    int x = (int)v;
    x += __builtin_amdgcn_update_dpp(0, x, 0x111, 0xF, 0xF, true);  // row_shr:1
    x += __builtin_amdgcn_update_dpp(0, x, 0x112, 0xF, 0xF, true);  // row_shr:2
    x += __builtin_amdgcn_update_dpp(0, x, 0x114, 0xF, 0xF, true);  // row_shr:4
    x += __builtin_amdgcn_update_dpp(0, x, 0x118, 0xF, 0xF, true);  // row_shr:8
    x += __builtin_amdgcn_update_dpp(0, x, 0x142, 0xF, 0xF, true);  // row_bcast:15
    x += __builtin_amdgcn_update_dpp(0, x, 0x143, 0xF, 0xF, true);  // row_bcast:31
    return (uint32_t)x;
}

// ---------------------------------------------------------------------------
// Fused selection kernel, one 1024-thread block per graph.
//  - bitonic sort on packed u64 (key<<16)|idx; barrier iff the step reads
//    data another wave wrote last step (R13 rule, validated).
//  - seeded search range [lb, ub] (R13): ub = max product key (cnt_gt(ub)=0
//    keeps the cntHi invariant exact); lb = min over rows of the row's
//    17th-largest product key (union >= K elements >= lb -> T >= lb).
//  - 4-ARY key-space search, ~13 rounds (R7-validated candidate/segment/
//    interval logic) with R14's DPP wave sums (VALU pipe) + triple-buffered
//    LDS counters via per-wave u32 atomicAdd (R7-validated buffering) ->
//    ONE barrier per round, no serial thread-0 phase; all threads update
//    lo/hi/cntHi/rlo/rhi uniformly from broadcast totals.
//    (R4/R7/R14 lesson: select is DS-pipe bound; __shfl is DS traffic.)
//  - collect ties (key == T, diag excluded) into LDS, dump to global.
// Product s_i*t_j is monotone in t_j for fixed s_i (IEEE multiply); sign of
// s_i picks suffix/prefix direction. All comparisons on exact product keys.
// ---------------------------------------------------------------------------
__global__ __launch_bounds__(NNODES)
void select_kernel(const float* __restrict__ s, const float* __restrict__ t,
                   uint32_t* __restrict__ Tout, uint32_t* __restrict__ Rout,
                   uint32_t* __restrict__ eqCntG, uint32_t* __restrict__ eqIdxG) {
    const int g = blockIdx.x, i = threadIdx.x;
    __shared__ uint64_t spk[NNODES];     // packed (key<<16)|idx, sorted ascending
    __shared__ float    tvs[NNODES];     // t values in key-ascending order
    __shared__ uint32_t wsum[16], wsum2[16];
    __shared__ uint32_t sCnt[3][3];      // triple-buffered per-round totals
    __shared__ uint32_t sLo, sHi, sEqCnt;
    __shared__ uint32_t sEqList[EQCAP];

    const float tv_i = t[g * NNODES + i];
    spk[i] = ((uint64_t)fkey(tv_i) << 16) | (uint32_t)i;
    if (i == 0) sEqCnt = 0u;
    if (i < 3) { sCnt[i][0] = 0u; sCnt[i][1] = 0u; sCnt[i][2] = 0u; }

    // ---- bitonic sort on packed u64 (R13 barrier rule) ----
    for (int k = 2; k <= NNODES; k <<= 1) {
        for (int j = k >> 1; j > 0; j >>= 1) {
            if ((j >= 64) || (j == 32 && k > 64)) __syncthreads();
            else                                  wavefence();
            int partner = i ^ j;
            if (partner > i) {
                bool asc = ((i & k) == 0);
                uint64_t a = spk[i], b = spk[partner];
                if ((a > b) == asc) { spk[i] = b; spk[partner] = a; }
            }
        }
    }
    __syncthreads();
    tvs[i] = inv_fkey((uint32_t)(spk[i] >> 16));

    const float sv = s[g * NNODES + i];
    const bool sneg = (__float_as_uint(sv) >> 31) != 0;
    const uint32_t kdiag = fkey(sv * tv_i);   // diagonal element (excluded)
    __syncthreads();                          // tvs visible to all

    // ---- seed [lb, ub] (R13 verbatim) ----
    {
        uint32_t m = fkey(sv * tvs[sneg ? 0 : (NNODES - 1)]);    // row max key
        uint32_t n = fkey(sv * tvs[sneg ? 16 : (NNODES - 17)]);  // row 17th-largest key
        for (int off = 32; off; off >>= 1) {
            uint32_t mm = __shfl_down(m, off); if (mm > m) m = mm;
            uint32_t nn = __shfl_down(n, off); if (nn < n) n = nn;
        }
        if ((i & 63) == 0) { wsum[i >> 6] = m; wsum2[i >> 6] = n; }
        __syncthreads();
        if (i == 0) {
            uint32_t ub = 0u, lb = 0xFFFFFFFFu;
            for (int w = 0; w < 16; ++w) {
                if (wsum[w]  > ub) ub = wsum[w];
                if (wsum2[w] < lb) lb = wsum2[w];
            }
            sLo = lb; sHi = ub;
        }
        __syncthreads();
    }

    // boundary search within [lo_,hi_): for s>=+0 rows, (key>cand) true on
    // suffix starting at b; for s<0 rows, prefix ending at b. b monotone in cand.
    auto srchRange = [&](uint32_t cand, int lo_, int hi_) -> int {
        while (lo_ < hi_) {
            int mid = (lo_ + hi_) >> 1;
            bool pred = fkey(sv * tvs[mid]) > cand;
            bool goLeft = sneg ? !pred : pred;
            if (goLeft) hi_ = mid; else lo_ = mid + 1;
        }
        return lo_;
    };

    // ---- 4-ary search: minimal T in [lo,hi] with cnt_gt(T) < K ----
    uint32_t lo = sLo, hi = sHi;     // uniform registers (read after barrier)
    uint32_t cntHi = 0u;             // cnt_gt(hi); exact at seed (hi=ub)
    int rlo = 0, rhi = NNODES;       // per-row interval covering b(c), c in [lo,hi]
    for (int it = 0; it < 17; ++it) {            // 4^17 > 2^32 worst case
        if (lo >= hi) break;                     // uniform early exit
        const uint32_t range = hi - lo;
        const uint32_t c0 = lo + (uint32_t)(((uint64_t)range * 1) >> 2);
        const uint32_t c1 = lo + (uint32_t)(((uint64_t)range * 2) >> 2);
        const uint32_t c2 = lo + (uint32_t)(((uint64_t)range * 3) >> 2);
        int b0, b1, b2;
        if (!sneg) {   // boundaries non-decreasing in cand: chain lower bounds
            b0 = srchRange(c0, rlo, rhi);
            b1 = srchRange(c1, b0,  rhi);
            b2 = srchRange(c2, b1,  rhi);
        } else {       // non-increasing: chain upper bounds
            b0 = srchRange(c0, rlo, rhi);
            b1 = srchRange(c1, rlo, b0);
            b2 = srchRange(c2, rlo, b1);
        }
        uint32_t n0 = sneg ? (uint32_t)b0 : (uint32_t)(NNODES - b0);
        uint32_t n1 = sneg ? (uint32_t)b1 : (uint32_t)(NNODES - b1);
        uint32_t n2 = sneg ? (uint32_t)b2 : (uint32_t)(NNODES - b2);
        if (kdiag > c0) n0--;                    // exclude diagonal
        if (kdiag > c1) n1--;
        if (kdiag > c2) n2--;
        const uint32_t r0 = wave_sum_dpp(n0);    // VALU pipe, zero DS
        const uint32_t r1 = wave_sum_dpp(n1);
        const uint32_t r2 = wave_sum_dpp(n2);
        uint32_t* buf = sCnt[it % 3];
        if ((i & 63) == 63) {                    // one lane per wave
            atomicAdd(&buf[0], r0);
            atomicAdd(&buf[1], r1);
            atomicAdd(&buf[2], r2);
        }
        if (i == 0) {                            // zero round it+1's buffer;
            uint32_t* nb = sCnt[(it + 1) % 3];   // last read at round it-2,
            nb[0] = 0u; nb[1] = 0u; nb[2] = 0u;  // barrier(it-1) separates (R7)
        }
        __syncthreads();                         // ONE barrier per round
        const uint32_t t0 = buf[0], t1 = buf[1], t2 = buf[2];  // broadcast reads
        // uniform update in every thread (R7-validated segment logic)
        if (t0 < TOPK)      { hi = c0; cntHi = t0;
                              if (!sneg) rhi = b0; else rlo = b0; }
        else if (t1 < TOPK) { lo = c0 + 1; hi = c1; cntHi = t1;
                              if (!sneg) { rlo = b0; rhi = b1; }
                              else       { rlo = b1; rhi = b0; } }
        else if (t2 < TOPK) { lo = c1 + 1; hi = c2; cntHi = t2;
                              if (!sneg) { rlo = b1; rhi = b2; }
                              else       { rlo = b2; rhi = b1; } }
        else                { lo = c2 + 1;
                              if (!sneg) rlo = b2; else rhi = b2; }
    }
    const uint32_t T = lo;                       // lo==hi; cnt_gt(T)==cntHi
    if (i == 0) { Tout[g] = T; Rout[g] = TOPK - cntHi; }

    // ---- collect ties (key == T), diagonal excluded (R11 verbatim) ----
    auto bound = [&](bool ge) -> int {
        int lo_ = 0, hi_ = NNODES;
        while (lo_ < hi_) {
            int mid = (lo_ + hi_) >> 1;
            uint32_t k = fkey(sv * tvs[mid]);
            bool pred = ge ? (k >= T) : (k > T);
            bool goLeft = sneg ? !pred : pred;
            if (goLeft) hi_ = mid; else lo_ = mid + 1;
        }
        return lo_;
    };
    int e0, e1;
    if (!sneg) { e0 = bound(true);  e1 = bound(false); }   // equals = [ge, gt)
    else       { e0 = bound(false); e1 = bound(true);  }   // equals = [gt, ge)
    for (int p = e0; p < e1; ++p) {
        uint32_t j = (uint32_t)(spk[p] & 0xFFFFu);         // original column idx
        if ((int)j == i) continue;
        uint32_t slot = atomicAdd(&sEqCnt, 1u);
        if (slot < EQCAP) sEqList[slot] = (uint32_t)(i * NNODES) + j;
    }
    __syncthreads();
    uint32_t E = sEqCnt; if (E > EQCAP) E = EQCAP;
    if (i == 0) eqCntG[g] = E;
    for (uint32_t p = i; p < E; p += NNODES) eqIdxG[g * EQCAP + p] = sEqList[p];
}

// ---------------------------------------------------------------------------
// Output write, R5/R11-validated shape (one block per output row, one float4
// store per thread), tie resolution folded into a cold path (R10/R11).
// out = 1 iff (key>T && j!=i) or (key==T && j!=i && rank_among_ties < R).
// ---------------------------------------------------------------------------
__global__ __launch_bounds__(256)
void write_kernel(const float* __restrict__ s, const float* __restrict__ t,
                  const uint32_t* __restrict__ Tin, const uint32_t* __restrict__ Rin,
                  const uint32_t* __restrict__ eqCntG, const uint32_t* __restrict__ eqIdxG,
                  float* __restrict__ out) {
    const int b = blockIdx.x;           // g*1024 + i
    const int g = b >> 10, i = b & 1023;
    const uint32_t T = Tin[g];
    const float sv = s[(size_t)g * NNODES + i];
    const vfloat4 tv = ((const vfloat4*)(t + (size_t)g * NNODES))[threadIdx.x];
    const int j0 = threadIdx.x * 4;
    const uint32_t k0 = fkey(sv * tv.x), k1 = fkey(sv * tv.y);
    const uint32_t k2 = fkey(sv * tv.z), k3 = fkey(sv * tv.w);
    vfloat4 o;
    o.x = (k0 > T && (j0 + 0) != i) ? 1.0f : 0.0f;
    o.y = (k1 > T && (j0 + 1) != i) ? 1.0f : 0.0f;
    o.z = (k2 > T && (j0 + 2) != i) ? 1.0f : 0.0f;
    o.w = (k3 > T && (j0 + 3) != i) ? 1.0f : 0.0f;
    if (k0 == T || k1 == T || k2 == T || k3 == T) {          // cold path: ties
        uint32_t E = eqCntG[g]; if (E > EQCAP) E = EQCAP;
        const uint32_t R = Rin[g];
        const uint32_t* eq = eqIdxG + (size_t)g * EQCAP;
        const uint32_t kk[4] = {k0, k1, k2, k3};
        #pragma unroll
        for (int q = 0; q < 4; ++q) {
            const uint32_t j = j0 + q;
            if (kk[q] == T && (int)j != i) {
                const uint32_t f = (uint32_t)i * NNODES + j;
                uint32_t rank = 0;
                for (uint32_t e2 = 0; e2 < E; ++e2) rank += (eq[e2] < f) ? 1u : 0u;
                if (rank < R) ((float*)&o)[q] = 1.0f;
            }
        }
    }
    ((vfloat4*)(out + (size_t)g * NNODES * NNODES + (size_t)i * NNODES))[threadIdx.x] = o;
}

extern "C" void kernel_launch(void* const* d_in, const int* in_sizes, int n_in,
                              void* d_out, int out_size, void* d_ws, size_t ws_size,
                              hipStream_t stream) {
    // inputs: x (unused), emb_s [G,N,1], emb_t [G,1,N] -- all float32
    const float* s = (const float*)d_in[1];
    const float* t = (const float*)d_in[2];
    float* out = (float*)d_out;

    char* ws = (char*)d_ws;
    uint32_t* Tbuf  = (uint32_t*)ws; ws += (size_t)NGRAPH * 4;
    uint32_t* Rbuf  = (uint32_t*)ws; ws += (size_t)NGRAPH * 4;
    uint32_t* eqCnt = (uint32_t*)ws; ws += (size_t)NGRAPH * 4;
    uint32_t* eqIdx = (uint32_t*)ws; ws += (size_t)NGRAPH * EQCAP * 4;

    select_kernel<<<NGRAPH, NNODES, 0, stream>>>(s, t, Tbuf, Rbuf, eqCnt, eqIdx);
    write_kernel<<<NGRAPH * NNODES, 256, 0, stream>>>(s, t, Tbuf, Rbuf, eqCnt, eqIdx, out);
}